// Round 2
// baseline (1567.669 us; speedup 1.0000x reference)
//
#include <hip/hip_runtime.h>
#include <hip/hip_bf16.h>
#include <stdint.h>

// Problem constants
#define TT 2048
#define NB 32
#define II 512
#define HH 1024
#define CC 8       // chunk length
#define MCH 256    // TT/CC chunks
#define RR 8192    // MCH*NB rows per scan step

typedef __attribute__((ext_vector_type(8))) short short8;
typedef __attribute__((ext_vector_type(4))) short short4v;
typedef __attribute__((ext_vector_type(4))) float f32x4;

__device__ __forceinline__ float b2f(short s) {
    union { unsigned u; float f; } x;
    x.u = ((unsigned)(unsigned short)s) << 16;
    return x.f;
}
__device__ __forceinline__ short f2b(float f) {   // RNE bf16 conversion
    unsigned u = __float_as_uint(f);
    u += 0x7fff + ((u >> 16) & 1);
    return (short)(u >> 16);
}

__device__ __forceinline__ void async16(const void* g, const void* l) {
    __builtin_amdgcn_global_load_lds(
        (const __attribute__((address_space(1))) void*)g,
        (__attribute__((address_space(3))) void*)l, 16, 0, 0);
}

// fp32 -> bf16 convert, 4 elems/thread
__global__ void cvt_kernel(const float* __restrict__ s, short* __restrict__ d, long n4) {
    long i = (long)blockIdx.x * blockDim.x + threadIdx.x;
    if (i < n4) {
        float4 v = ((const float4*)s)[i];
        short4v o;
        o.x = f2b(v.x); o.y = f2b(v.y); o.z = f2b(v.z); o.w = f2b(v.w);
        *(short4v*)(d + 4 * i) = o;
    }
}

// 1024x1024 bf16 transpose (for power GEMMs with the B^T-layout GEMM)
__global__ void transpose_kernel(const short* __restrict__ s, short* __restrict__ d) {
    __shared__ short tile[32][33];
    int tx = threadIdx.x & 31, ty = threadIdx.x >> 5;
    int bx = blockIdx.x * 32, by = blockIdx.y * 32;
    for (int y = ty; y < 32; y += 8) tile[y][tx] = s[(long)(by + y) * HH + bx + tx];
    __syncthreads();
    for (int y = ty; y < 32; y += 8) d[(long)(bx + y) * HH + by + tx] = tile[tx][y];
}

// Seed: s_{i,1} = proj_{iC} -> sbuf1 (bf16 chain) AND out0 fp32 at t=iC+1
__global__ void seed_kernel(const short* __restrict__ projb, short* __restrict__ sbuf1,
                            float* __restrict__ out0) {
    int r = blockIdx.x;            // 0..RR-1 = i*32+n
    int i = r >> 5, n = r & 31;
    int c0 = threadIdx.x * 4;
    short4v v = *(const short4v*)(projb + ((long)(n * TT + i * CC)) * HH + c0);
    *(short4v*)(sbuf1 + (long)r * HH + c0) = v;
    float4 f;
    f.x = b2f(v.x); f.y = b2f(v.y); f.z = b2f(v.z); f.w = b2f(v.w);
    *(float4*)(out0 + ((long)(n * TT + i * CC + 1)) * HH + c0) = f;
}

// Shifted chunk-total buffers for the boundary convolution:
//   sh1[i] = (i==0) ? proj_0 : SC[i-1]
//   sh2[i] = (i==0) ? 0 : (i==1 ? proj_0 : SC[i-2])
// b_i = sh1[i] + W^CC * sh2[i]  (truncates W^{2CC} term, proven OK at CC=8)
__global__ void prep_kernel(const short* __restrict__ projb, const short* __restrict__ SC,
                            short* __restrict__ sh1, short* __restrict__ sh2) {
    int r = blockIdx.x;
    int i = r >> 5, n = r & 31;
    int c0 = threadIdx.x * 4;
    short4v z = {0, 0, 0, 0};
    short4v p0 = *(const short4v*)(projb + ((long)n * TT) * HH + c0);
    short4v v1 = (i == 0) ? p0 : *(const short4v*)(SC + ((long)((i - 1) * NB + n)) * HH + c0);
    short4v v2 = (i == 0) ? z : ((i == 1) ? p0 : *(const short4v*)(SC + ((long)((i - 2) * NB + n)) * HH + c0));
    *(short4v*)(sh1 + (long)r * HH + c0) = v1;
    *(short4v*)(sh2 + (long)r * HH + c0) = v2;
}

// C[r,col] = sum_k A[r,k]*B[col,k] (+bias) (+src); 128xBN tile, BK=32, 4 waves,
// 2-phase double-buffered LDS pipeline (stage t+1 overlaps compute t; single
// vmcnt(0)+barrier drain per phase — guide T3 minimum form, statically-named
// LDS buffers so the compiler can disambiguate ds_read vs global_load_lds).
// SRC: 0 none; 1 bf16 src, row remap sr=(r>>5)*ssI+(r&31)*ssN+soff;
//      2 fp32 src at dest location (read-add-write, col paged by 1024; implies NF32=2)
// WMODE: 0 none; 1 bf16 dest identity rows; 2 paged bf16 dest (col>>10 selects page)
// NF32 (SRC!=2): 0 none, 1 f0, 2 f0+f1, dest remap dr=(r>>5)*dsI+(r&31)*dsN+doff
template<int BN, int SRC, bool BIAS, int NF32, int WMODE>
__global__ __launch_bounds__(256) void gemm_bt(
    const short* __restrict__ A, const short* __restrict__ B, int K,
    const void* src, const float* __restrict__ bias,
    float* f0, float* f1, short* __restrict__ bd,
    int dsI, int dsN, int doff, int ssI, int ssN, int soff)
{
    constexpr int NJ = BN / 32;            // b-frags per wave (128->4, 64->2)
    __shared__ __align__(16) short As0[128 * 32];
    __shared__ __align__(16) short As1[128 * 32];
    __shared__ __align__(16) short Bs0[BN * 32];
    __shared__ __align__(16) short Bs1[BN * 32];
    const int tid = threadIdx.x;
    const int wave = tid >> 6, lane = tid & 63;
    const int wm = wave & 1, wn = wave >> 1;
    const int quad = lane >> 4, l16 = lane & 15;
    const long row0 = (long)blockIdx.x * 128, col0 = (long)blockIdx.y * BN;

    const short* ag = A + (row0 + (tid >> 2)) * K + (tid & 3) * 8;
    const short* bg = B + (col0 + (tid >> 2)) * K + (tid & 3) * 8;
    const long k64 = (long)64 * K;
    const int lw = wave * 512;             // lane*16B appended by HW

    auto STAGE = [&](short* Asb, short* Bsb, int kk) {
        async16(ag + kk,       Asb + lw);
        async16(ag + kk + k64, Asb + lw + 2048);
        async16(bg + kk,       Bsb + lw);
        if constexpr (BN == 128)
            async16(bg + kk + k64, Bsb + lw + 2048);
    };

    f32x4 zero = {0.f, 0.f, 0.f, 0.f};
    f32x4 acc[4][NJ];
#pragma unroll
    for (int i = 0; i < 4; i++)
#pragma unroll
        for (int j = 0; j < NJ; j++) acc[i][j] = zero;

    auto COMPUTE = [&](const short* Asb, const short* Bsb) {
        short8 af[4], bf[NJ];
#pragma unroll
        for (int i = 0; i < 4; i++)
            af[i] = *(const short8*)(Asb + (wm * 64 + i * 16 + l16) * 32 + quad * 8);
#pragma unroll
        for (int j = 0; j < NJ; j++)
            bf[j] = *(const short8*)(Bsb + (wn * (BN / 2) + j * 16 + l16) * 32 + quad * 8);
#pragma unroll
        for (int i = 0; i < 4; i++)
#pragma unroll
            for (int j = 0; j < NJ; j++)
                acc[i][j] = __builtin_amdgcn_mfma_f32_16x16x32_bf16(af[i], bf[j], acc[i][j], 0, 0, 0);
    };

    const int nt = K / 32;                 // always even (K=512 or 1024)
    STAGE(As0, Bs0, 0);
    __syncthreads();                       // drain vmcnt(0): buf0 ready
    for (int t = 0; t < nt; t += 2) {
        STAGE(As1, Bs1, (t + 1) * 32);     // prefetch overlaps compute below
        COMPUTE(As0, Bs0);
        __syncthreads();                   // drain: buf1 staged, buf0 readers done
        if (t + 2 < nt) STAGE(As0, Bs0, (t + 2) * 32);
        COMPUTE(As1, Bs1);
        __syncthreads();
    }

    // Epilogue. C/D layout (verified m89/m91): col = lane&15, row = quad*4 + reg.
#pragma unroll
    for (int i = 0; i < 4; i++) {
#pragma unroll
        for (int j = 0; j < NJ; j++) {
            const int colg = (int)col0 + wn * (BN / 2) + j * 16 + l16;
            const int page = colg >> 10;
            const int colp = colg & 1023;
            float bv = 0.f;
            if (BIAS) bv = bias[colg];
#pragma unroll
            for (int v = 0; v < 4; v++) {
                const int row = (int)row0 + wm * 64 + i * 16 + quad * 4 + v;
                float val = acc[i][j][v] + bv;
                if constexpr (SRC == 1) {
                    const long sr = (long)(row >> 5) * ssI + (long)(row & 31) * ssN + soff;
                    val += b2f(((const short*)src)[sr * HH + colg]);
                }
                if constexpr (SRC == 2) {
                    const long dr = (long)(row >> 5) * dsI + (long)(row & 31) * dsN + doff + page;
                    val += f0[dr * HH + colp];
                    f0[dr * HH + colp] = val;
                    f1[dr * HH + colp] = val;
                } else if constexpr (NF32 >= 1) {
                    const long dr = (long)(row >> 5) * dsI + (long)(row & 31) * dsN + doff;
                    f0[dr * HH + colg] = val;
                    if constexpr (NF32 == 2) f1[dr * HH + colg] = val;
                }
                if constexpr (WMODE == 1) bd[(long)row * HH + colg] = f2b(val);
                else if constexpr (WMODE == 2)
                    bd[(long)page * (HH * HH) + (long)row * HH + colp] = f2b(val);
            }
        }
    }
}

extern "C" void kernel_launch(void* const* d_in, const int* in_sizes, int n_in,
                              void* d_out, int out_size, void* d_ws, size_t ws_size,
                              hipStream_t stream)
{
    const float* x   = (const float*)d_in[0];
    const float* wih = (const float*)d_in[1];
    const float* bih = (const float*)d_in[2];
    const float* whh = (const float*)d_in[3];
    float* out0 = (float*)d_out;
    float* out1 = out0 + (long)NB * TT * HH;

    // workspace carve (195 MiB total, below previous 201 MiB)
    char* p = (char*)d_ws;
    auto alloc = [&](size_t bytes) -> char* {
        char* r = p;
        p += (bytes + 255) & ~(size_t)255;
        return r;
    };
    short* projb = (short*)alloc((size_t)NB * TT * HH * 2);  // 128 MiB bf16 proj
    short* wihb  = (short*)alloc((size_t)HH * II * 2);       // 1 MiB
    short* whhb  = (short*)alloc((size_t)HH * HH * 2);       // 2 MiB
    short* xb    = (short*)alloc((size_t)NB * TT * II * 2);  // 64 MiB, dead after proj
    // overlay scan buffers on xb region: 4 slots x 16 MiB.
    // slot0: sbuf0 / sh1        slot1: sbuf1 / sh2
    // slot2: SCb -> powcat (8 pages W^1..W^8; SCb dead after prep)
    // slot3: hbuf0 (boundary b, bf16)
    const size_t SB = (size_t)RR * HH * 2;                   // 16 MiB
    char* ov = (char*)xb;
    short* sbuf0  = (short*)(ov + 0 * SB);
    short* sbuf1  = (short*)(ov + 1 * SB);
    short* SCb    = (short*)(ov + 2 * SB);
    short* hbuf0  = (short*)(ov + 3 * SB);
    short* sh1    = sbuf0;
    short* sh2    = sbuf1;
    short* powcat = SCb;                     // 8 pages of HH*HH bf16
    short* powsT  = (short*)out1;            // 4 transpose pages (8 MiB scratch in
                                             // out1; dead before boundary writes out1)
    const long PG = (long)HH * HH;

    dim3 blk(256);
    const dim3 sg(RR / 128, HH / 128);       // scan GEMM grid: (64,8) = 512 blocks

    // 1) converts
    long n4x = (long)NB * TT * II / 4;
    cvt_kernel<<<dim3((unsigned)((n4x + 255) / 256)), blk, 0, stream>>>(x, xb, n4x);
    long n4a = (long)HH * II / 4;
    cvt_kernel<<<dim3((unsigned)((n4a + 255) / 256)), blk, 0, stream>>>(wih, wihb, n4a);
    long n4b = (long)HH * HH / 4;
    cvt_kernel<<<dim3((unsigned)((n4b + 255) / 256)), blk, 0, stream>>>(whh, whhb, n4b);

    // 2) proj = x @ w_ih^T + b  (bf16 out)
    gemm_bt<128, 0, true, 0, 1><<<dim3(512, 8), blk, 0, stream>>>(
        xb, wihb, II, nullptr, bih, nullptr, nullptr, projb, 0, 0, 0, 0, 0, 0);

    // 3) seed s_{i,1} = p_{iC} (bf16 chain + fp32 to out0 at t=iC+1)
    seed_kernel<<<dim3(RR), blk, 0, stream>>>(projb, sbuf1, out0);

    // 4) pass 1: s_{i,c} = W s_{i,c-1} + p_{iC+c-1}, c=2..CC.
    //    c<=CC-1: bf16 chain + fp32 s -> out0 at t=iC+c; c=CC: SC totals only.
    for (int c = 2; c < CC; ++c) {
        const short* a = (c & 1) ? sbuf0 : sbuf1;
        short* o = (c & 1) ? sbuf1 : sbuf0;
        gemm_bt<128, 1, false, 1, 1><<<sg, blk, 0, stream>>>(
            a, whhb, HH, projb, nullptr, out0, nullptr, o,
            CC, TT, c, CC, TT, c - 1);
    }
    gemm_bt<128, 1, false, 0, 1><<<sg, blk, 0, stream>>>(
        sbuf1, whhb, HH, projb, nullptr, nullptr, nullptr, SCb,
        0, 0, 0, CC, TT, CC - 1);

    // 5) prep shifted chunk totals (slots 0/1 reused as sh1/sh2)
    prep_kernel<<<dim3(RR), blk, 0, stream>>>(projb, SCb, sh1, sh2);

    // 6) powers W^1..W^8 into powcat pages (slot2; SCb now dead).
    //    W2=W*W; [W3|W4]=W2*[W^T;W2^T]; [W5..W8]=W4*[W^T;W2^T;W3^T;W4^T]
    dim3 tg(32, 32);
    cvt_kernel<<<dim3((unsigned)((n4b + 255) / 256)), blk, 0, stream>>>(whh, powcat, n4b);
    transpose_kernel<<<tg, blk, 0, stream>>>(whhb, powsT);                   // T0 = W^T
    gemm_bt<64, 0, false, 0, 2><<<dim3(8, 16), blk, 0, stream>>>(
        whhb, powsT, HH, nullptr, nullptr, nullptr, nullptr, powcat + 1 * PG,
        0, 0, 0, 0, 0, 0);                                                   // W2
    transpose_kernel<<<tg, blk, 0, stream>>>(powcat + 1 * PG, powsT + 1 * PG); // T1
    gemm_bt<64, 0, false, 0, 2><<<dim3(8, 32), blk, 0, stream>>>(
        powcat + 1 * PG, powsT, HH, nullptr, nullptr, nullptr, nullptr, powcat + 2 * PG,
        0, 0, 0, 0, 0, 0);                                                   // W3,W4
    transpose_kernel<<<tg, blk, 0, stream>>>(powcat + 2 * PG, powsT + 2 * PG); // T2
    transpose_kernel<<<tg, blk, 0, stream>>>(powcat + 3 * PG, powsT + 3 * PG); // T3
    gemm_bt<64, 0, false, 0, 2><<<dim3(8, 64), blk, 0, stream>>>(
        powcat + 3 * PG, powsT, HH, nullptr, nullptr, nullptr, nullptr, powcat + 4 * PG,
        0, 0, 0, 0, 0, 0);                                                   // W5..W8

    // 7) boundary: b_i = sh1 + W^CC * sh2 -> out(t=iC) x2 (fp32) + hbuf0 (bf16)
    gemm_bt<128, 1, false, 2, 1><<<sg, blk, 0, stream>>>(
        sh2, powcat + 7 * PG, HH, sh1, nullptr, out0, out1, hbuf0,
        CC, TT, 0, NB, 1, 0);

    // 8) pass 2 (parallel over c): h_{iC+c} = s_{i,c} + W^c b_i, c=1..CC-1.
    //    ONE GEMM: A = b (RR x H), B = [W^1|...|W^7] (7H x H), epilogue reads
    //    s from out0 (fp32), adds, writes out0 and out1.
    gemm_bt<128, 2, false, 2, 0><<<dim3(RR / 128, (CC - 1) * HH / 128), blk, 0, stream>>>(
        hbuf0, powcat, HH, nullptr, nullptr, out0, out1, nullptr,
        CC, TT, 1, 0, 0, 0);
}